// Round 9
// baseline (118.848 us; speedup 1.0000x reference)
//
#include <hip/hip_runtime.h>

// MLP3D fused, MI355X gfx950 — round 9.
// vs r8 (47.7us, MfmaUtil 31%, 2 blocks/CU): the stall is phase-level
// serialization (2 waves/SIMD, barrier-aligned phases), not per-kb latency.
// -> 3 blocks/CU: M_PB=64 + separate E-buffer (LDS 44KB) + lb(256,3) with a
// register budget engineered to ~156 (acc64 + A-2buf 32 + B-dbuf 32 + misc).
// Keeps: per-wave-contiguous A layout, B double-buffer, part-head fold,
// bias-in-acc, pkrtz. Layer-first A-frags issue before the preceding
// epilogue/barrier (phase-start L2 latency hidden). Grid 2048 -> 8 blocks/CU,
// 3 co-resident generations de-align phases and fill barrier stalls.

#define NPTS 131072
#define M_PB 64
#define AST 264   // act row stride in halves (256+8)
#define EST 72    // E-buffer row stride in halves (64+8)

typedef _Float16 half8   __attribute__((ext_vector_type(8)));
typedef _Float16 half4_t __attribute__((ext_vector_type(4)));
typedef __fp16   fp16x2  __attribute__((ext_vector_type(2)));
typedef float    float4_t __attribute__((ext_vector_type(4)));

// ---- prep: W (f32 [K][256]) -> f16 per-wave-contiguous fragment layout ----
// dst[(((s*KB + kb)*4 + tn)*64 + l)*8 + j] = W[(kb*32 + (l>>4)*8 + j)*256 + s*64 + tn*16 + (l&15)]
__global__ void prep(const float* __restrict__ W0, const float* __restrict__ W1,
                     const float* __restrict__ W2, _Float16* __restrict__ ws) {
  int id = blockIdx.x * 256 + threadIdx.x;   // 147456 total
  _Float16 v;
  if (id < 16384) {            // W0sw: 4 slices x 2 kb x 4 tn x 512
    int e = id, j = e & 7, l = (e >> 3) & 63, tn = (e >> 9) & 3, kb = (e >> 11) & 1, s = e >> 12;
    int k = kb * 32 + (l >> 4) * 8 + j, n = s * 64 + tn * 16 + (l & 15);
    v = (k < 63) ? (_Float16)W0[k * 256 + n] : (_Float16)0.f;
  } else if (id < 81920) {     // W1sw: 4 x 8 x 4 x 512
    int e = id - 16384, j = e & 7, l = (e >> 3) & 63, tn = (e >> 9) & 3, kb = (e >> 11) & 7, s = e >> 14;
    int k = kb * 32 + (l >> 4) * 8 + j, n = s * 64 + tn * 16 + (l & 15);
    v = (_Float16)W1[k * 256 + n];
  } else {                     // W2sw
    int e = id - 81920, j = e & 7, l = (e >> 3) & 63, tn = (e >> 9) & 3, kb = (e >> 11) & 7, s = e >> 14;
    int k = kb * 32 + (l >> 4) * 8 + j, n = s * 64 + tn * 16 + (l & 15);
    v = (_Float16)W2[k * 256 + n];
  }
  ws[id] = v;
}

__device__ __forceinline__ half4_t pack4(float a, float b, float cc, float d) {
  fp16x2 p0 = __builtin_amdgcn_cvt_pkrtz(a, b);
  fp16x2 p1 = __builtin_amdgcn_cvt_pkrtz(cc, d);
  half4_t h;
  h[0] = (_Float16)p0[0]; h[1] = (_Float16)p0[1];
  h[2] = (_Float16)p1[0]; h[3] = (_Float16)p1[1];
  return h;
}

__global__ __launch_bounds__(256, 3) void mlp_main(
    const float* __restrict__ coords,
    const _Float16* __restrict__ W0sw,
    const _Float16* __restrict__ W1sw,
    const _Float16* __restrict__ W2sw,
    const float* __restrict__ b0, const float* __restrict__ b1,
    const float* __restrict__ b2,
    const float* __restrict__ Wocc, const float* __restrict__ bocc,
    const float* __restrict__ Wc, const float* __restrict__ bc,
    float* __restrict__ out) {
  __shared__ _Float16 ebuf[M_PB * EST];   // E only (K=64) — separate buffer
  __shared__ _Float16 actX[M_PB * AST];   // h -> t1
  __shared__ float occ_s[4][M_PB];

  const int t = threadIdx.x;
  const int w = t >> 6;          // wave = neuron slice [64w,64w+64) = part id
  const int l = t & 63;
  const int c = l & 15;
  const int q = l >> 4;
  const int m0 = blockIdx.x * M_PB;

  // ---- positional encoding: wave w computes k in [16w,16w+16), lane=point ----
  {
    const float* cp = coords + (size_t)(m0 + l) * 3;
    float x0 = cp[0], x1 = cp[1], x2 = cp[2];
    float v[16];
#pragma unroll
    for (int u = 0; u < 16; ++u) {
      int k = 16 * w + u;   // wave-uniform
      float r;
      if (k >= 63) r = 0.f;
      else if (k < 3) r = (k == 0) ? x0 : (k == 1 ? x1 : x2);
      else {
        int kk = k - 3;
        int f = kk / 6;
        int rem = kk - 6 * f;
        int s = (rem >= 3) ? 1 : 0;
        int i3 = rem - 3 * s;
        float xi = (i3 == 0) ? x0 : (i3 == 1 ? x1 : x2);
        float arg = xi * (float)(1 << f);
        float nn = rintf(arg * 0.15915494309189535f);
        float rr = fmaf(nn, -6.28318548202514648f, arg);
        rr = fmaf(nn, 1.7484555e-7f, rr);
        r = s ? __cosf(rr) : __sinf(rr);
      }
      v[u] = r;
    }
    half8 e0, e1;
#pragma unroll
    for (int u = 0; u < 4; ++u) {
      fp16x2 p = __builtin_amdgcn_cvt_pkrtz(v[2 * u], v[2 * u + 1]);
      e0[2 * u] = (_Float16)p[0]; e0[2 * u + 1] = (_Float16)p[1];
      fp16x2 p2 = __builtin_amdgcn_cvt_pkrtz(v[8 + 2 * u], v[9 + 2 * u]);
      e1[2 * u] = (_Float16)p2[0]; e1[2 * u + 1] = (_Float16)p2[1];
    }
    *(half8*)&ebuf[l * EST + 16 * w] = e0;
    *(half8*)&ebuf[l * EST + 16 * w + 8] = e1;
  }

  half8 A[2][4];   // rotating A-fragment buffers (32 VGPR)
  // L0 A-frags: issue BEFORE the E barrier (global loads independent of LDS)
  {
    const _Float16* wb = W0sw + (size_t)w * 4096 + l * 8;
#pragma unroll
    for (int tn = 0; tn < 4; ++tn) {
      A[0][tn] = *(const half8*)(wb + tn * 512);
      A[1][tn] = *(const half8*)(wb + 2048 + tn * 512);
    }
  }
  __syncthreads();                                   // (1) E ready

  float4_t acc[4][4];
  const _Float16* ap = actX + c * AST + q * 8;
  const _Float16* ep = ebuf + c * EST + q * 8;
  const int w2 = 2 * w;
  // L1 kb order: masked pair (2w, 2w+1) first, then the rest
  auto kbof = [&](int j) {
    return (j < 2) ? (w2 + j) : ((j - 2) + ((j - 2) >= w2 ? 2 : 0));
  };
  const _Float16* wb1 = W1sw + (size_t)w * 16384 + l * 8;
  const _Float16* wb2 = W2sw + (size_t)w * 16384 + l * 8;

  // ---- layer 0: h = E @ W0 + b0 (no relu), K=64 ----
  {
    half8 bc0[4], bc1[4];
#pragma unroll
    for (int tm = 0; tm < 4; ++tm) bc0[tm] = *(const half8*)(ep + tm * 16 * EST);
#pragma unroll
    for (int tm = 0; tm < 4; ++tm) bc1[tm] = *(const half8*)(ep + tm * 16 * EST + 32);
#pragma unroll
    for (int tn = 0; tn < 4; ++tn) {
      float4_t bz = *(const float4_t*)(b0 + 64 * w + tn * 16 + q * 4);
#pragma unroll
      for (int tm = 0; tm < 4; ++tm) acc[tn][tm] = bz;
    }
#pragma unroll
    for (int tn = 0; tn < 4; ++tn)
#pragma unroll
      for (int tm = 0; tm < 4; ++tm)
        acc[tn][tm] = __builtin_amdgcn_mfma_f32_16x16x32_f16(A[0][tn], bc0[tm], acc[tn][tm], 0, 0, 0);
#pragma unroll
    for (int tn = 0; tn < 4; ++tn)
#pragma unroll
      for (int tm = 0; tm < 4; ++tm)
        acc[tn][tm] = __builtin_amdgcn_mfma_f32_16x16x32_f16(A[1][tn], bc1[tm], acc[tn][tm], 0, 0, 0);
  }
  // L1 first A-frags: issue now, latency hidden by epilogue + barrier
#pragma unroll
  for (int p = 0; p < 2; ++p) {
    const _Float16* pa = wb1 + kbof(p) * 2048;
#pragma unroll
    for (int tn = 0; tn < 4; ++tn) A[p][tn] = *(const half8*)(pa + tn * 512);
  }
  // epilogue: h -> actX (no E-read drain barrier needed: separate buffers)
#pragma unroll
  for (int tn = 0; tn < 4; ++tn)
#pragma unroll
    for (int tm = 0; tm < 4; ++tm) {
      float4_t v = acc[tn][tm];
      *(half4_t*)&actX[(tm * 16 + c) * AST + 64 * w + tn * 16 + q * 4] =
          pack4(v[0], v[1], v[2], v[3]);
    }
  __syncthreads();                                   // (2) h ready

  // ---- layer 1 (+ part head): snapshot after j==1 ----
  {
    float bcw = bc[w];
#pragma unroll
    for (int tn = 0; tn < 4; ++tn) {
      float4_t bz = *(const float4_t*)(b1 + 64 * w + tn * 16 + q * 4);
#pragma unroll
      for (int tm = 0; tm < 4; ++tm) acc[tn][tm] = bz;
    }
    half8 bcur[4];
#pragma unroll
    for (int tm = 0; tm < 4; ++tm)
      bcur[tm] = *(const half8*)(ap + tm * 16 * AST + kbof(0) * 32);
#pragma unroll
    for (int j = 0; j < 8; ++j) {
      half8 bnxt[4];
      if (j + 1 < 8) {                       // B(j+1) issues before MFMAs of j
        const int kbn = kbof(j + 1);
#pragma unroll
        for (int tm = 0; tm < 4; ++tm)
          bnxt[tm] = *(const half8*)(ap + tm * 16 * AST + kbn * 32);
      }
#pragma unroll
      for (int tn = 0; tn < 4; ++tn)
#pragma unroll
        for (int tm = 0; tm < 4; ++tm)
          acc[tn][tm] = __builtin_amdgcn_mfma_f32_16x16x32_f16(
              A[j & 1][tn], bcur[tm], acc[tn][tm], 0, 0, 0);
      if (j == 1) {
        // snapshot: acc = b1 + (x*mask_w) @ W1-slice -> class head for part w
        float pcls[4] = {0.f, 0.f, 0.f, 0.f};
#pragma unroll
        for (int tn = 0; tn < 4; ++tn) {
          float4_t wcv = *(const float4_t*)(Wc + 256 * w + 64 * w + tn * 16 + q * 4);
#pragma unroll
          for (int tm = 0; tm < 4; ++tm) {
            float4_t v = acc[tn][tm];
#pragma unroll
            for (int r = 0; r < 4; ++r) pcls[tm] += fmaxf(v[r], 0.f) * wcv[r];
          }
        }
#pragma unroll
        for (int tm = 0; tm < 4; ++tm) {
          float s = pcls[tm];
          s += __shfl_xor(s, 16, 64);
          s += __shfl_xor(s, 32, 64);
          if (l < 16)
            out[(size_t)NPTS + (size_t)(m0 + tm * 16 + c) * 4 + w] = s + bcw;
        }
      }
      if (j + 2 < 8) {   // A(j+2) -> buffer (j&1): AFTER its consumption above
        const _Float16* pa = wb1 + kbof(j + 2) * 2048;
#pragma unroll
        for (int tn = 0; tn < 4; ++tn) A[j & 1][tn] = *(const half8*)(pa + tn * 512);
      }
#pragma unroll
      for (int tm = 0; tm < 4; ++tm) bcur[tm] = bnxt[tm];
    }
  }
  // L2 first A-frags: issue now (A buffers free), hidden by barrier + epilogue
#pragma unroll
  for (int p = 0; p < 2; ++p)
#pragma unroll
    for (int tn = 0; tn < 4; ++tn)
      A[p][tn] = *(const half8*)(wb2 + p * 2048 + tn * 512);
  __syncthreads();                                   // (3) all h reads done
#pragma unroll
  for (int tn = 0; tn < 4; ++tn)
#pragma unroll
    for (int tm = 0; tm < 4; ++tm) {
      float4_t v = acc[tn][tm];
      *(half4_t*)&actX[(tm * 16 + c) * AST + 64 * w + tn * 16 + q * 4] =
          pack4(fmaxf(v[0], 0.f), fmaxf(v[1], 0.f), fmaxf(v[2], 0.f), fmaxf(v[3], 0.f));
    }
  __syncthreads();                                   // (4) t1 ready

  // ---- layer 2 + occ head ----
  {
#pragma unroll
    for (int tn = 0; tn < 4; ++tn) {
      float4_t bz = *(const float4_t*)(b2 + 64 * w + tn * 16 + q * 4);
#pragma unroll
      for (int tm = 0; tm < 4; ++tm) acc[tn][tm] = bz;
    }
    half8 bcur[4];
#pragma unroll
    for (int tm = 0; tm < 4; ++tm) bcur[tm] = *(const half8*)(ap + tm * 16 * AST);
#pragma unroll
    for (int kb = 0; kb < 8; ++kb) {
      half8 bnxt[4];
      if (kb + 1 < 8) {
#pragma unroll
        for (int tm = 0; tm < 4; ++tm)
          bnxt[tm] = *(const half8*)(ap + tm * 16 * AST + (kb + 1) * 32);
      }
#pragma unroll
      for (int tn = 0; tn < 4; ++tn)
#pragma unroll
        for (int tm = 0; tm < 4; ++tm)
          acc[tn][tm] = __builtin_amdgcn_mfma_f32_16x16x32_f16(
              A[kb & 1][tn], bcur[tm], acc[tn][tm], 0, 0, 0);
      if (kb + 2 < 8) {
#pragma unroll
        for (int tn = 0; tn < 4; ++tn)
          A[kb & 1][tn] = *(const half8*)(wb2 + (kb + 2) * 2048 + tn * 512);
      }
#pragma unroll
      for (int tm = 0; tm < 4; ++tm) bcur[tm] = bnxt[tm];
    }
    float pocc[4] = {0.f, 0.f, 0.f, 0.f};
#pragma unroll
    for (int tn = 0; tn < 4; ++tn) {
      float4_t wov = *(const float4_t*)(Wocc + 64 * w + tn * 16 + q * 4);
#pragma unroll
      for (int tm = 0; tm < 4; ++tm) {
        float4_t v = acc[tn][tm];
#pragma unroll
        for (int r = 0; r < 4; ++r) pocc[tm] += fmaxf(v[r], 0.f) * wov[r];
      }
    }
#pragma unroll
    for (int tm = 0; tm < 4; ++tm) {
      float s = pocc[tm];
      s += __shfl_xor(s, 16, 64);
      s += __shfl_xor(s, 32, 64);
      if (l < 16) occ_s[w][tm * 16 + c] = s;
    }
  }
  __syncthreads();                                   // (5) occ partials ready
  if (t < M_PB) {
    out[m0 + t] = occ_s[0][t] + occ_s[1][t] + occ_s[2][t] + occ_s[3][t] + bocc[0];
  }
}

extern "C" void kernel_launch(void* const* d_in, const int* in_sizes, int n_in,
                              void* d_out, int out_size, void* d_ws, size_t ws_size,
                              hipStream_t stream) {
  const float* coords = (const float*)d_in[0];
  const float* W0   = (const float*)d_in[1];
  const float* b0   = (const float*)d_in[2];
  const float* W1   = (const float*)d_in[3];
  const float* b1   = (const float*)d_in[4];
  const float* W2   = (const float*)d_in[5];
  const float* b2   = (const float*)d_in[6];
  const float* Wocc = (const float*)d_in[7];
  const float* bocc = (const float*)d_in[8];
  const float* Wc   = (const float*)d_in[9];
  const float* bc   = (const float*)d_in[10];
  float* out = (float*)d_out;

  _Float16* ws = (_Float16*)d_ws;       // W0sw[16384] | W1sw[65536] | W2sw[65536]
  _Float16* W0sw = ws;
  _Float16* W1sw = ws + 16384;
  _Float16* W2sw = ws + 81920;

  prep<<<576, 256, 0, stream>>>(W0, W1, W2, ws);
  mlp_main<<<NPTS / M_PB, 256, 0, stream>>>(coords, W0sw, W1sw, W2sw,
                                            b0, b1, b2, Wocc, bocc, Wc, bc, out);
}

// Round 10
// 116.724 us; speedup vs baseline: 1.0182x; 1.0182x over previous
//
#include <hip/hip_runtime.h>

// MLP3D fused, MI355X gfx950 — round 10.
// vs r9 (50us, MfmaUtil 32%): ONE change — LDS activations stored
// MFMA-FRAGMENT-MAJOR ([tm][kb][lane][8]) instead of row-major+pad.
// r1-r9's B-reads ds_read_b128 at (tm*16+c)*264 + q*8 alias banks 4-way+
// (SQ_LDS_BANK_CONFLICT pinned at 3.4M every round ~= +11.6 cyc/b128);
// the LDS pipe was the saturated shared resource (r8->r9: +50% TLP, dur
// flat). Fragment-major makes every B-read lane-linear (base + 16*lane,
// conflict-free) with compile-time immediate offsets; embed/epilogue
// writes land at the bank aggregate minimum. LDS 41KB -> still 3 blk/CU.
// Keeps r9: M_PB=64, per-wave-contiguous A layout + reg rotation, B dbuf,
// part-head fold, bias-in-acc, pkrtz, lb(256,3).

#define NPTS 131072
#define M_PB 64

typedef _Float16 half8   __attribute__((ext_vector_type(8)));
typedef _Float16 half4_t __attribute__((ext_vector_type(4)));
typedef __fp16   fp16x2  __attribute__((ext_vector_type(2)));
typedef float    float4_t __attribute__((ext_vector_type(4)));

// ---- prep: W (f32 [K][256]) -> f16 per-wave-contiguous fragment layout ----
// dst[(((s*KB + kb)*4 + tn)*64 + l)*8 + j] = W[(kb*32 + (l>>4)*8 + j)*256 + s*64 + tn*16 + (l&15)]
__global__ void prep(const float* __restrict__ W0, const float* __restrict__ W1,
                     const float* __restrict__ W2, _Float16* __restrict__ ws) {
  int id = blockIdx.x * 256 + threadIdx.x;   // 147456 total
  _Float16 v;
  if (id < 16384) {            // W0sw: 4 slices x 2 kb x 4 tn x 512
    int e = id, j = e & 7, l = (e >> 3) & 63, tn = (e >> 9) & 3, kb = (e >> 11) & 1, s = e >> 12;
    int k = kb * 32 + (l >> 4) * 8 + j, n = s * 64 + tn * 16 + (l & 15);
    v = (k < 63) ? (_Float16)W0[k * 256 + n] : (_Float16)0.f;
  } else if (id < 81920) {     // W1sw: 4 x 8 x 4 x 512
    int e = id - 16384, j = e & 7, l = (e >> 3) & 63, tn = (e >> 9) & 3, kb = (e >> 11) & 7, s = e >> 14;
    int k = kb * 32 + (l >> 4) * 8 + j, n = s * 64 + tn * 16 + (l & 15);
    v = (_Float16)W1[k * 256 + n];
  } else {                     // W2sw
    int e = id - 81920, j = e & 7, l = (e >> 3) & 63, tn = (e >> 9) & 3, kb = (e >> 11) & 7, s = e >> 14;
    int k = kb * 32 + (l >> 4) * 8 + j, n = s * 64 + tn * 16 + (l & 15);
    v = (_Float16)W2[k * 256 + n];
  }
  ws[id] = v;
}

__device__ __forceinline__ half4_t pack4(float a, float b, float cc, float d) {
  fp16x2 p0 = __builtin_amdgcn_cvt_pkrtz(a, b);
  fp16x2 p1 = __builtin_amdgcn_cvt_pkrtz(cc, d);
  half4_t h;
  h[0] = (_Float16)p0[0]; h[1] = (_Float16)p0[1];
  h[2] = (_Float16)p1[0]; h[3] = (_Float16)p1[1];
  return h;
}

__global__ __launch_bounds__(256, 3) void mlp_main(
    const float* __restrict__ coords,
    const _Float16* __restrict__ W0sw,
    const _Float16* __restrict__ W1sw,
    const _Float16* __restrict__ W2sw,
    const float* __restrict__ b0, const float* __restrict__ b1,
    const float* __restrict__ b2,
    const float* __restrict__ Wocc, const float* __restrict__ bocc,
    const float* __restrict__ Wc, const float* __restrict__ bc,
    float* __restrict__ out) {
  // fragment-major: frag (tm,kb) at (tm*KB+kb)*512 + lane*8 halves
  __shared__ _Float16 ebuf[4096];    // E: 4 tm x 2 kb x 512   (8 KB)
  __shared__ _Float16 actX[16384];   // h/t1: 4 tm x 8 kb x 512 (32 KB)
  __shared__ float occ_s[4][M_PB];

  const int t = threadIdx.x;
  const int w = t >> 6;          // wave = neuron slice [64w,64w+64) = part id
  const int l = t & 63;
  const int c = l & 15;
  const int q = l >> 4;
  const int m0 = blockIdx.x * M_PB;

  // ---- positional encoding: wave w computes k in [16w,16w+16), lane=point ----
  {
    const float* cp = coords + (size_t)(m0 + l) * 3;
    float x0 = cp[0], x1 = cp[1], x2 = cp[2];
    float v[16];
#pragma unroll
    for (int u = 0; u < 16; ++u) {
      int k = 16 * w + u;   // wave-uniform
      float r;
      if (k >= 63) r = 0.f;
      else if (k < 3) r = (k == 0) ? x0 : (k == 1 ? x1 : x2);
      else {
        int kk = k - 3;
        int f = kk / 6;
        int rem = kk - 6 * f;
        int s = (rem >= 3) ? 1 : 0;
        int i3 = rem - 3 * s;
        float xi = (i3 == 0) ? x0 : (i3 == 1 ? x1 : x2);
        float arg = xi * (float)(1 << f);
        float nn = rintf(arg * 0.15915494309189535f);
        float rr = fmaf(nn, -6.28318548202514648f, arg);
        rr = fmaf(nn, 1.7484555e-7f, rr);
        r = s ? __cosf(rr) : __sinf(rr);
      }
      v[u] = r;
    }
#pragma unroll
    for (int uh = 0; uh < 2; ++uh) {
      half8 ev;
#pragma unroll
      for (int u = 0; u < 4; ++u) {
        fp16x2 p = __builtin_amdgcn_cvt_pkrtz(v[8 * uh + 2 * u], v[8 * uh + 2 * u + 1]);
        ev[2 * u] = (_Float16)p[0]; ev[2 * u + 1] = (_Float16)p[1];
      }
      // k0 = 16w + 8uh -> kb = k0>>5, qq = (k0>>3)&3; frag = (l>>4)*2 + kb
      int k0 = 16 * w + 8 * uh;
      int off = (((l >> 4) * 2 + (k0 >> 5)) * 512) + (((l & 15) + 16 * ((k0 >> 3) & 3)) * 8);
      *(half8*)&ebuf[off] = ev;
    }
  }

  half8 A[2][4];   // rotating A-fragment buffers (32 VGPR)
  // L0 A-frags: issue BEFORE the E barrier (global loads independent of LDS)
  {
    const _Float16* wb = W0sw + (size_t)w * 4096 + l * 8;
#pragma unroll
    for (int tn = 0; tn < 4; ++tn) {
      A[0][tn] = *(const half8*)(wb + tn * 512);
      A[1][tn] = *(const half8*)(wb + 2048 + tn * 512);
    }
  }
  __syncthreads();                                   // (1) E ready

  float4_t acc[4][4];
  const int w2 = 2 * w;
  // L1 kb order: masked pair (2w, 2w+1) first, then the rest
  auto kbof = [&](int j) {
    return (j < 2) ? (w2 + j) : ((j - 2) + ((j - 2) >= w2 ? 2 : 0));
  };
  const _Float16* wb1 = W1sw + (size_t)w * 16384 + l * 8;
  const _Float16* wb2 = W2sw + (size_t)w * 16384 + l * 8;

  // epilogue scatter offset for acc[tn][tm] half4 (point c, neurons
  // n0 = 64w+16tn+4q..+3): frag = tm*8 + 2w + (tn>>1);
  // lane-in-frag = c | (((2tn + (q>>1))&3)<<4); j0 = 4(q&1)
  auto epoff = [&](int tn, int tm) {
    return (tm * 8 + w2 + (tn >> 1)) * 512 +
           (c + 16 * ((2 * tn + (q >> 1)) & 3)) * 8 + 4 * (q & 1);
  };

  // ---- layer 0: h = E @ W0 + b0 (no relu), K=64 ----
  {
    half8 bc0[4], bc1[4];
#pragma unroll
    for (int tm = 0; tm < 4; ++tm) bc0[tm] = *(const half8*)&ebuf[(tm * 2) * 512 + l * 8];
#pragma unroll
    for (int tm = 0; tm < 4; ++tm) bc1[tm] = *(const half8*)&ebuf[(tm * 2 + 1) * 512 + l * 8];
#pragma unroll
    for (int tn = 0; tn < 4; ++tn) {
      float4_t bz = *(const float4_t*)(b0 + 64 * w + tn * 16 + q * 4);
#pragma unroll
      for (int tm = 0; tm < 4; ++tm) acc[tn][tm] = bz;
    }
#pragma unroll
    for (int tn = 0; tn < 4; ++tn)
#pragma unroll
      for (int tm = 0; tm < 4; ++tm)
        acc[tn][tm] = __builtin_amdgcn_mfma_f32_16x16x32_f16(A[0][tn], bc0[tm], acc[tn][tm], 0, 0, 0);
#pragma unroll
    for (int tn = 0; tn < 4; ++tn)
#pragma unroll
      for (int tm = 0; tm < 4; ++tm)
        acc[tn][tm] = __builtin_amdgcn_mfma_f32_16x16x32_f16(A[1][tn], bc1[tm], acc[tn][tm], 0, 0, 0);
  }
  // L1 first A-frags: issue now, latency hidden by epilogue + barrier
#pragma unroll
  for (int p = 0; p < 2; ++p) {
    const _Float16* pa = wb1 + kbof(p) * 2048;
#pragma unroll
    for (int tn = 0; tn < 4; ++tn) A[p][tn] = *(const half8*)(pa + tn * 512);
  }
  // epilogue: h -> actX (separate buffers: no E-read drain barrier needed)
#pragma unroll
  for (int tn = 0; tn < 4; ++tn)
#pragma unroll
    for (int tm = 0; tm < 4; ++tm) {
      float4_t v = acc[tn][tm];
      *(half4_t*)&actX[epoff(tn, tm)] = pack4(v[0], v[1], v[2], v[3]);
    }
  __syncthreads();                                   // (2) h ready

  // ---- layer 1 (+ part head): snapshot after j==1 ----
  {
    float bcw = bc[w];
#pragma unroll
    for (int tn = 0; tn < 4; ++tn) {
      float4_t bz = *(const float4_t*)(b1 + 64 * w + tn * 16 + q * 4);
#pragma unroll
      for (int tm = 0; tm < 4; ++tm) acc[tn][tm] = bz;
    }
    half8 bcur[4];
#pragma unroll
    for (int tm = 0; tm < 4; ++tm)
      bcur[tm] = *(const half8*)&actX[(tm * 8 + kbof(0)) * 512 + l * 8];
#pragma unroll
    for (int j = 0; j < 8; ++j) {
      half8 bnxt[4];
      if (j + 1 < 8) {                       // B(j+1) issues before MFMAs of j
        const int kbn = kbof(j + 1);
#pragma unroll
        for (int tm = 0; tm < 4; ++tm)
          bnxt[tm] = *(const half8*)&actX[(tm * 8 + kbn) * 512 + l * 8];
      }
#pragma unroll
      for (int tn = 0; tn < 4; ++tn)
#pragma unroll
        for (int tm = 0; tm < 4; ++tm)
          acc[tn][tm] = __builtin_amdgcn_mfma_f32_16x16x32_f16(
              A[j & 1][tn], bcur[tm], acc[tn][tm], 0, 0, 0);
      if (j == 1) {
        // snapshot: acc = b1 + (x*mask_w) @ W1-slice -> class head for part w
        float pcls[4] = {0.f, 0.f, 0.f, 0.f};
#pragma unroll
        for (int tn = 0; tn < 4; ++tn) {
          float4_t wcv = *(const float4_t*)(Wc + 256 * w + 64 * w + tn * 16 + q * 4);
#pragma unroll
          for (int tm = 0; tm < 4; ++tm) {
            float4_t v = acc[tn][tm];
#pragma unroll
            for (int r = 0; r < 4; ++r) pcls[tm] += fmaxf(v[r], 0.f) * wcv[r];
          }
        }
#pragma unroll
        for (int tm = 0; tm < 4; ++tm) {
          float s = pcls[tm];
          s += __shfl_xor(s, 16, 64);
          s += __shfl_xor(s, 32, 64);
          if (l < 16)
            out[(size_t)NPTS + (size_t)(m0 + tm * 16 + c) * 4 + w] = s + bcw;
        }
      }
      if (j + 2 < 8) {   // A(j+2) -> buffer (j&1): AFTER its consumption above
        const _Float16* pa = wb1 + kbof(j + 2) * 2048;
#pragma unroll
        for (int tn = 0; tn < 4; ++tn) A[j & 1][tn] = *(const half8*)(pa + tn * 512);
      }
#pragma unroll
      for (int tm = 0; tm < 4; ++tm) bcur[tm] = bnxt[tm];
    }
  }
  // L2 first A-frags: issue now (A buffers free), hidden by barrier + epilogue
#pragma unroll
  for (int p = 0; p < 2; ++p)
#pragma unroll
    for (int tn = 0; tn < 4; ++tn)
      A[p][tn] = *(const half8*)(wb2 + p * 2048 + tn * 512);
  __syncthreads();                                   // (3) all h reads done
#pragma unroll
  for (int tn = 0; tn < 4; ++tn)
#pragma unroll
    for (int tm = 0; tm < 4; ++tm) {
      float4_t v = acc[tn][tm];
      *(half4_t*)&actX[epoff(tn, tm)] =
          pack4(fmaxf(v[0], 0.f), fmaxf(v[1], 0.f), fmaxf(v[2], 0.f), fmaxf(v[3], 0.f));
    }
  __syncthreads();                                   // (4) t1 ready

  // ---- layer 2 + occ head ----
  {
#pragma unroll
    for (int tn = 0; tn < 4; ++tn) {
      float4_t bz = *(const float4_t*)(b2 + 64 * w + tn * 16 + q * 4);
#pragma unroll
      for (int tm = 0; tm < 4; ++tm) acc[tn][tm] = bz;
    }
    half8 bcur[4];
#pragma unroll
    for (int tm = 0; tm < 4; ++tm) bcur[tm] = *(const half8*)&actX[(tm * 8) * 512 + l * 8];
#pragma unroll
    for (int kb = 0; kb < 8; ++kb) {
      half8 bnxt[4];
      if (kb + 1 < 8) {
#pragma unroll
        for (int tm = 0; tm < 4; ++tm)
          bnxt[tm] = *(const half8*)&actX[(tm * 8 + kb + 1) * 512 + l * 8];
      }
#pragma unroll
      for (int tn = 0; tn < 4; ++tn)
#pragma unroll
        for (int tm = 0; tm < 4; ++tm)
          acc[tn][tm] = __builtin_amdgcn_mfma_f32_16x16x32_f16(
              A[kb & 1][tn], bcur[tm], acc[tn][tm], 0, 0, 0);
      if (kb + 2 < 8) {
#pragma unroll
        for (int tn = 0; tn < 4; ++tn)
          A[kb & 1][tn] = *(const half8*)(wb2 + (kb + 2) * 2048 + tn * 512);
      }
#pragma unroll
      for (int tm = 0; tm < 4; ++tm) bcur[tm] = bnxt[tm];
    }
    float pocc[4] = {0.f, 0.f, 0.f, 0.f};
#pragma unroll
    for (int tn = 0; tn < 4; ++tn) {
      float4_t wov = *(const float4_t*)(Wocc + 64 * w + tn * 16 + q * 4);
#pragma unroll
      for (int tm = 0; tm < 4; ++tm) {
        float4_t v = acc[tn][tm];
#pragma unroll
        for (int r = 0; r < 4; ++r) pocc[tm] += fmaxf(v[r], 0.f) * wov[r];
      }
    }
#pragma unroll
    for (int tm = 0; tm < 4; ++tm) {
      float s = pocc[tm];
      s += __shfl_xor(s, 16, 64);
      s += __shfl_xor(s, 32, 64);
      if (l < 16) occ_s[w][tm * 16 + c] = s;
    }
  }
  __syncthreads();                                   // (5) occ partials ready
  if (t < M_PB) {
    out[m0 + t] = occ_s[0][t] + occ_s[1][t] + occ_s[2][t] + occ_s[3][t] + bocc[0];
  }
}

extern "C" void kernel_launch(void* const* d_in, const int* in_sizes, int n_in,
                              void* d_out, int out_size, void* d_ws, size_t ws_size,
                              hipStream_t stream) {
  const float* coords = (const float*)d_in[0];
  const float* W0   = (const float*)d_in[1];
  const float* b0   = (const float*)d_in[2];
  const float* W1   = (const float*)d_in[3];
  const float* b1   = (const float*)d_in[4];
  const float* W2   = (const float*)d_in[5];
  const float* b2   = (const float*)d_in[6];
  const float* Wocc = (const float*)d_in[7];
  const float* bocc = (const float*)d_in[8];
  const float* Wc   = (const float*)d_in[9];
  const float* bc   = (const float*)d_in[10];
  float* out = (float*)d_out;

  _Float16* ws = (_Float16*)d_ws;       // W0sw[16384] | W1sw[65536] | W2sw[65536]
  _Float16* W0sw = ws;
  _Float16* W1sw = ws + 16384;
  _Float16* W2sw = ws + 81920;

  prep<<<576, 256, 0, stream>>>(W0, W1, W2, ws);
  mlp_main<<<NPTS / M_PB, 256, 0, stream>>>(coords, W0sw, W1sw, W2sw,
                                            b0, b1, b2, Wocc, bocc, Wc, bc, out);
}